// Round 17
// baseline (369.541 us; speedup 1.0000x reference)
//
#include <hip/hip_runtime.h>

// MultilayeredNetwork v15 = R16 (360us) + NONTEMPORAL packed-stream loads in
// k_layer. R16 PMC: k_layer FETCH=100MB/layer ~ 2x the compulsory floor
// (8 XCD x 6.4MB state + 25.6MB packed); excess = state lines evicted by the
// read-once packed stream. NT loads mark packed as last-use -> L2 keeps state.
// Same bits loaded -> numerics bitwise-identical (unbiased rn @2^27 int32).
// Build path byte-identical to R16 (no bcount; fixed-cap slabs; 4-way
// replicated passA; bscan2; passB tight scatter).

#define N_NEURONS 100000
#define NNZ_CNT   3200000
#define N_SENSORY 5000
#define BATCH     16
#define T_LAYERS  8
#define THRESH    0.01f
#define STEEP     5.0f

#define NB (N_NEURONS * BATCH)
#define NT (N_NEURONS * T_LAYERS)
#define ST (N_SENSORY * T_LAYERS)

#define FXS32     134217728.0f             /* 2^27: exact fp32 prescale */
#define FXI32     7.450580596923828e-9f    /* 2^-27 exact */

#define LBITS   9
#define BROWS   (1 << LBITS)                           /* 512 rows per bucket */
#define NBUCKET ((N_NEURONS + BROWS - 1) / BROWS)      /* 196 */
#define BCAP    18432                                  /* bucket slab cap (mean 16327 + 16sigma) */
#define EPB     4096                                   /* edges per passA block */
#define NBLK_A  ((NNZ_CNT + EPB - 1) / EPB)            /* 782 */

#define FXSCALE   17592186044416.0f        /* fallback path only (2^44) */
#define FXINV     (1.0 / 17592186044416.0)

__device__ __forceinline__ float thresh_clamp_inp(float u) {
    u = (u >= THRESH) ? u : 0.0f;
    return fminf(u, 1.0f);
}
__device__ __forceinline__ float activate(float y) {
    y = (y >= THRESH) ? y : 0.0f;
    return tanhf(STEEP * y);
}

// ---------------- build (byte-identical to R16) ----------------

__global__ void k_init(const float* __restrict__ inp, float* __restrict__ state0,
                       int* __restrict__ bcur) {
    int i = blockIdx.x * blockDim.x + threadIdx.x;
    if (i >= NB) return;
    int n = i >> 4, b = i & 15;
    float v = 0.0f;
    if (n < N_SENSORY) v = thresh_clamp_inp(inp[b * ST + n * T_LAYERS + 0]);
    state0[i] = v;
    if (i < NBUCKET) bcur[i] = i * BCAP;
}

__global__ void __launch_bounds__(1024) k_passA(const float* __restrict__ vals,
                                                const int* __restrict__ rows,
                                                const int* __restrict__ cols,
                                                int* bcur,
                                                int2* __restrict__ slab) {
    __shared__ int cnt[4][NBUCKET];
    __shared__ int base[4][NBUCKET];
    const int e0 = blockIdx.x * EPB;
    const int q  = threadIdx.x >> 8;            // quarter 0..3
    for (int i = threadIdx.x; i < 4 * NBUCKET; i += 1024) (&cnt[0][0])[i] = 0;
    __syncthreads();
    #pragma unroll
    for (int i = 0; i < EPB / 1024; ++i) {
        int e = e0 + i * 1024 + threadIdx.x;
        if (e < NNZ_CNT) atomicAdd(&cnt[q][rows[e] >> LBITS], 1);
    }
    __syncthreads();
    for (int i = threadIdx.x; i < NBUCKET; i += 1024) {
        int c0 = cnt[0][i], c1 = cnt[1][i], c2 = cnt[2][i], c3 = cnt[3][i];
        int tot = c0 + c1 + c2 + c3;
        int g = (tot > 0) ? atomicAdd(&bcur[i], tot) : 0;
        base[0][i] = g;
        base[1][i] = g + c0;
        base[2][i] = g + c0 + c1;
        base[3][i] = g + c0 + c1 + c2;
        cnt[0][i] = 0; cnt[1][i] = 0; cnt[2][i] = 0; cnt[3][i] = 0;
    }
    __syncthreads();
    #pragma unroll
    for (int i = 0; i < EPB / 1024; ++i) {
        int e = e0 + i * 1024 + threadIdx.x;
        if (e < NNZ_CNT) {
            int r = rows[e];
            int k = r >> LBITS;
            int pos = base[q][k] + atomicAdd(&cnt[q][k], 1);
            slab[pos] = make_int2((cols[e] << LBITS) | (r & (BROWS - 1)),
                                  __float_as_int(vals[e] * FXS32));   // exact prescale
        }
    }
}

__global__ void k_bscan2(const int* __restrict__ bcur, int* __restrict__ bbase,
                         int* __restrict__ row_ptr) {
    __shared__ int lds[256];
    int tid = threadIdx.x;
    int c = (tid < NBUCKET) ? (bcur[tid] - tid * BCAP) : 0;
    lds[tid] = c;
    __syncthreads();
    for (int off = 1; off < 256; off <<= 1) {
        int add = (tid >= off) ? lds[tid - off] : 0;
        __syncthreads();
        lds[tid] += add;
        __syncthreads();
    }
    if (tid < NBUCKET) bbase[tid] = lds[tid] - c;   // tight base into packed
    if (tid == 0) { bbase[NBUCKET] = NNZ_CNT; row_ptr[N_NEURONS] = NNZ_CNT; }
}

__global__ void __launch_bounds__(1024) k_passB(const int* __restrict__ bcur,
                                                const int* __restrict__ bbase,
                                                const int2* __restrict__ slab,
                                                int2* __restrict__ packed,
                                                int* __restrict__ row_ptr) {
    __shared__ int cnt[BROWS];
    __shared__ int scn[BROWS];
    const int tid = threadIdx.x;
    const int k  = blockIdx.x;
    const int r0 = k * BROWS;
    const int nr = min(BROWS, N_NEURONS - r0);
    const int S0 = k * BCAP;                       // slab region
    const int SC = bcur[k] - S0;                   // exact bucket count
    const int Q0 = bbase[k];                       // tight packed base
    for (int i = tid; i < BROWS; i += 1024) cnt[i] = 0;
    __syncthreads();
    for (int i = tid; i < SC; i += 1024)
        atomicAdd(&cnt[slab[S0 + i].x & (BROWS - 1)], 1);
    __syncthreads();
    if (tid < BROWS) scn[tid] = cnt[tid];
    __syncthreads();
    for (int off = 1; off < BROWS; off <<= 1) {
        int add = (tid < BROWS && tid >= off) ? scn[tid - off] : 0;
        __syncthreads();
        if (tid < BROWS) scn[tid] += add;
        __syncthreads();
    }
    if (tid < BROWS) {
        int ex = Q0 + scn[tid] - cnt[tid];          // exclusive row base (tight)
        if (tid < nr) row_ptr[r0 + tid] = ex;
        scn[tid] = ex;                              // cursor
    }
    __syncthreads();
    for (int i = tid; i < SC; i += 1024) {
        int2 pe = slab[S0 + i];
        int d = atomicAdd(&scn[pe.x & (BROWS - 1)], 1);
        packed[d] = make_int2(pe.x >> LBITS, pe.y); // (col, prescaled val)
    }
}

// ---------------- fused per-layer SpMM + activation ----------------
// R14 shape + prefetch; packed stream loaded NONTEMPORAL (read-once -> don't
// evict the L2-resident state working set). 16-lane group per row; LDS
// same-address broadcast; int32-rn accumulate (vals prescaled 2^27).
__global__ void __launch_bounds__(256) k_layer(const int* __restrict__ row_ptr,
                                               const long long* __restrict__ packed64,
                                               const float* __restrict__ state_in,
                                               const float* __restrict__ inp,
                                               float* __restrict__ plane_out,
                                               int t) {
    __shared__ long long ebuf[16][17];          // [group][slot], +1 pad
    const int tid = threadIdx.x;
    const int g = tid >> 4, b = tid & 15;
    const int r = blockIdx.x * 16 + g;          // 6250*16 == N_NEURONS exactly
    const int s = row_ptr[r], e = row_ptr[r + 1];
    int acc = 0;
    int idx0 = s + b;
    long long pe = (idx0 < e) ? __builtin_nontemporal_load(&packed64[idx0]) : 0LL;
    for (int base = s; base < e; base += 16) {
        int nidx = base + 16 + b;               // prefetch next batch NOW
        long long pe_next = (nidx < e) ? __builtin_nontemporal_load(&packed64[nidx]) : 0LL;
        ebuf[g][b] = pe;                        // wave-lockstep, in-order DS pipe
        #pragma unroll
        for (int j = 0; j < 16; ++j) {
            long long qv = ebuf[g][j];          // 16-lane same-address broadcast read
            int   qc = (int)(qv & 0xffffffffLL);
            float v  = __int_as_float((int)(qv >> 32));
            float prod = v * state_in[qc * BATCH + b];
            acc += __float2int_rn(prod);        // UNBIASED quantization at 2^-28
        }
        pe = pe_next;
    }
    float y = (float)acc * FXI32;
    float a = activate(y);
    if (t < T_LAYERS - 1) {
        if (r < N_SENSORY) a += thresh_clamp_inp(inp[b * ST + r * T_LAYERS + (t + 1)]);
        a = fminf(a, 1.0f);                     // off-sensory no-op (|tanh|<1)
    }
    plane_out[r * BATCH + b] = a;
}

// ---------------- planes[t][n][b] -> out[b][n][t] ----------------
__global__ void k_out(const float* __restrict__ planes, float* __restrict__ out) {
    int i = blockIdx.x * blockDim.x + threadIdx.x;
    if (i >= NB) return;
    int n = i >> 4, b = i & 15;
    float4 o0, o1;
    o0.x = planes[0 * NB + i]; o0.y = planes[1 * NB + i];
    o0.z = planes[2 * NB + i]; o0.w = planes[3 * NB + i];
    o1.x = planes[4 * NB + i]; o1.y = planes[5 * NB + i];
    o1.z = planes[6 * NB + i]; o1.w = planes[7 * NB + i];
    float4* dst = (float4*)&out[b * NT + n * T_LAYERS];
    dst[0] = o0; dst[1] = o1;
}

// ---------------- fallback (atomic fixed-point path, 19.2 MB ws) ----------------
__global__ void k2_init(const float* __restrict__ inp, float* __restrict__ state,
                        long long* __restrict__ acc) {
    int stride = gridDim.x * blockDim.x;
    for (int i = blockIdx.x * blockDim.x + threadIdx.x; i < NB; i += stride) {
        int n = i >> 4, b = i & 15;
        float v = 0.0f;
        if (n < N_SENSORY) v = thresh_clamp_inp(inp[b * ST + n * T_LAYERS + 0]);
        state[i] = v;
        acc[i]   = 0LL;
    }
}
__global__ void __launch_bounds__(256) k2_spmm(const float* __restrict__ vals,
                                               const int* __restrict__ rows,
                                               const int* __restrict__ cols,
                                               const float* __restrict__ state,
                                               long long* acc) {
    int tid = blockIdx.x * blockDim.x + threadIdx.x;
    int b = tid & 15;
    int e = tid >> 4;
    int estride = (gridDim.x * blockDim.x) >> 4;
    for (; e < NNZ_CNT; e += estride) {
        float xv = state[cols[e] * BATCH + b];
        long long fx = llrintf(vals[e] * xv * FXSCALE);
        if (fx != 0LL)
            atomicAdd((unsigned long long*)&acc[rows[e] * BATCH + b], (unsigned long long)fx);
    }
}
__global__ void k2_act_inject(long long* acc, const float* __restrict__ inp,
                              float* __restrict__ state, float* __restrict__ out, int t) {
    int stride = gridDim.x * blockDim.x;
    for (int i = blockIdx.x * blockDim.x + threadIdx.x; i < NB; i += stride) {
        int n = i >> 4, b = i & 15;
        float y = (float)((double)acc[i] * FXINV);
        acc[i] = 0LL;
        float v = activate(y);
        if (n < N_SENSORY) v += thresh_clamp_inp(inp[b * ST + n * T_LAYERS + (t + 1)]);
        v = fminf(v, 1.0f);
        state[i] = v;
        out[b * NT + n * T_LAYERS + t] = v;
    }
}
__global__ void k2_act_final(const long long* __restrict__ acc, float* __restrict__ out) {
    int stride = gridDim.x * blockDim.x;
    for (int i = blockIdx.x * blockDim.x + threadIdx.x; i < NB; i += stride) {
        int n = i >> 4, b = i & 15;
        float y = (float)((double)acc[i] * FXINV);
        out[b * NT + n * T_LAYERS + (T_LAYERS - 1)] = activate(y);
    }
}

extern "C" void kernel_launch(void* const* d_in, const int* in_sizes, int n_in,
                              void* d_out, int out_size, void* d_ws, size_t ws_size,
                              hipStream_t stream) {
    const float* inputs = (const float*)d_in[0];
    const float* vals   = (const float*)d_in[1];
    const int*   rows   = (const int*)  d_in[2];
    const int*   cols   = (const int*)  d_in[3];
    float* out = (float*)d_out;

    const size_t sz_planes = (size_t)T_LAYERS * NB * 4;   // 51.2 MB (slab 28.9MB aliases planes[0..4])
    const size_t sz_packed = (size_t)NNZ_CNT * 8;         // 25.6 MB
    const size_t sz_rowptr = ((size_t)N_NEURONS + 2) * 4;
    const size_t sz_bt     = (size_t)(NBUCKET + 8) * 4;
    const size_t REQ = sz_planes + sz_packed + sz_rowptr + 2 * sz_bt;

    const int block = 256;

    if (ws_size >= REQ) {
        char* ws = (char*)d_ws;
        float* planes  = (float*)ws;
        int2*  packed  = (int2*)(ws + sz_planes);
        int*   row_ptr = (int*)(ws + sz_planes + sz_packed);
        int*   bbase   = (int*)(ws + sz_planes + sz_packed + sz_rowptr);
        int*   bcur    = (int*)(ws + sz_planes + sz_packed + sz_rowptr + sz_bt);
        float* state0  = planes + (size_t)(T_LAYERS - 1) * NB;  // planes[7], consumed at t=0
        int2*  slab    = (int2*)planes;   // 28.9 MB build scratch; dead before layers

        const int grid_nb = (NB + block - 1) / block;           // 6250

        k_init<<<grid_nb, block, 0, stream>>>(inputs, state0, bcur);
        k_passA<<<NBLK_A, 1024, 0, stream>>>(vals, rows, cols, bcur, slab);
        k_bscan2<<<1, 256, 0, stream>>>(bcur, bbase, row_ptr);
        k_passB<<<NBUCKET, 1024, 0, stream>>>(bcur, bbase, slab, packed, row_ptr);

        for (int t = 0; t < T_LAYERS; ++t) {
            const float* sin_ = (t == 0) ? state0 : planes + (size_t)(t - 1) * NB;
            k_layer<<<grid_nb, block, 0, stream>>>(row_ptr, (const long long*)packed,
                                                   sin_, inputs,
                                                   planes + (size_t)t * NB, t);
        }
        k_out<<<grid_nb, block, 0, stream>>>(planes, out);
    } else {
        long long* acc   = (long long*)d_ws;
        float*     state = (float*)(acc + NB);
        const int grid_ew = 2048, grid_sp = 2048;
        k2_init<<<grid_ew, block, 0, stream>>>(inputs, state, acc);
        for (int t = 0; t < T_LAYERS; ++t) {
            k2_spmm<<<grid_sp, block, 0, stream>>>(vals, rows, cols, state, acc);
            if (t < T_LAYERS - 1)
                k2_act_inject<<<grid_ew, block, 0, stream>>>(acc, inputs, state, out, t);
            else
                k2_act_final<<<grid_ew, block, 0, stream>>>(acc, out);
        }
    }
}

// Round 18
// 359.512 us; speedup vs baseline: 1.0279x; 1.0279x over previous
//
#include <hip/hip_runtime.h>

// MultilayeredNetwork FINAL (= R16, 360us verified best).
// R17 post-mortem: nontemporal packed loads were neutral-to-negative (370us);
// reverted. Structure:
//   build: k_init (state0 + fixed-cap bucket cursors; bcount deleted, counts
//          are data-constants) -> passA (two-level LDS-binned scatter, 4-way
//          replicated counters, PRESCALED vals) -> bscan2 (tight bases) ->
//          passB (per-bucket LDS row-hist+scan -> row_ptr + tight CSR)
//   per t: k_layer — 16-lane group per row, packed-stream prefetch, LDS
//          same-address broadcast, UNBIASED __float2int_rn @2^27 int32 acc
//          (order-independent -> bitwise-deterministic graph replays)
//   final: k_out — planes[t][n][b] -> out[b][n][t], float4 stores.
// Perf budget (PMC): 8x k_layer ~250us (~3.3TB/s random-gather service, the
// practical floor for 6.4MB state > 4MB per-XCD L2), passA ~55 (latency-bound
// scatter), passB ~20, out ~18, misc ~15.

#define N_NEURONS 100000
#define NNZ_CNT   3200000
#define N_SENSORY 5000
#define BATCH     16
#define T_LAYERS  8
#define THRESH    0.01f
#define STEEP     5.0f

#define NB (N_NEURONS * BATCH)
#define NT (N_NEURONS * T_LAYERS)
#define ST (N_SENSORY * T_LAYERS)

#define FXS32     134217728.0f             /* 2^27: exact fp32 prescale */
#define FXI32     7.450580596923828e-9f    /* 2^-27 exact */

#define LBITS   9
#define BROWS   (1 << LBITS)                           /* 512 rows per bucket */
#define NBUCKET ((N_NEURONS + BROWS - 1) / BROWS)      /* 196 */
#define BCAP    18432                                  /* bucket slab cap (mean 16327 + 16sigma) */
#define EPB     4096                                   /* edges per passA block */
#define NBLK_A  ((NNZ_CNT + EPB - 1) / EPB)            /* 782 */

#define FXSCALE   17592186044416.0f        /* fallback path only (2^44) */
#define FXINV     (1.0 / 17592186044416.0)

__device__ __forceinline__ float thresh_clamp_inp(float u) {
    u = (u >= THRESH) ? u : 0.0f;
    return fminf(u, 1.0f);
}
__device__ __forceinline__ float activate(float y) {
    y = (y >= THRESH) ? y : 0.0f;
    return tanhf(STEEP * y);
}

// ---------------- build ----------------

__global__ void k_init(const float* __restrict__ inp, float* __restrict__ state0,
                       int* __restrict__ bcur) {
    int i = blockIdx.x * blockDim.x + threadIdx.x;
    if (i >= NB) return;
    int n = i >> 4, b = i & 15;
    float v = 0.0f;
    if (n < N_SENSORY) v = thresh_clamp_inp(inp[b * ST + n * T_LAYERS + 0]);
    state0[i] = v;
    if (i < NBUCKET) bcur[i] = i * BCAP;
}

__global__ void __launch_bounds__(1024) k_passA(const float* __restrict__ vals,
                                                const int* __restrict__ rows,
                                                const int* __restrict__ cols,
                                                int* bcur,
                                                int2* __restrict__ slab) {
    __shared__ int cnt[4][NBUCKET];
    __shared__ int base[4][NBUCKET];
    const int e0 = blockIdx.x * EPB;
    const int q  = threadIdx.x >> 8;            // quarter 0..3
    for (int i = threadIdx.x; i < 4 * NBUCKET; i += 1024) (&cnt[0][0])[i] = 0;
    __syncthreads();
    #pragma unroll
    for (int i = 0; i < EPB / 1024; ++i) {
        int e = e0 + i * 1024 + threadIdx.x;
        if (e < NNZ_CNT) atomicAdd(&cnt[q][rows[e] >> LBITS], 1);
    }
    __syncthreads();
    for (int i = threadIdx.x; i < NBUCKET; i += 1024) {
        int c0 = cnt[0][i], c1 = cnt[1][i], c2 = cnt[2][i], c3 = cnt[3][i];
        int tot = c0 + c1 + c2 + c3;
        int g = (tot > 0) ? atomicAdd(&bcur[i], tot) : 0;
        base[0][i] = g;
        base[1][i] = g + c0;
        base[2][i] = g + c0 + c1;
        base[3][i] = g + c0 + c1 + c2;
        cnt[0][i] = 0; cnt[1][i] = 0; cnt[2][i] = 0; cnt[3][i] = 0;
    }
    __syncthreads();
    #pragma unroll
    for (int i = 0; i < EPB / 1024; ++i) {
        int e = e0 + i * 1024 + threadIdx.x;
        if (e < NNZ_CNT) {
            int r = rows[e];
            int k = r >> LBITS;
            int pos = base[q][k] + atomicAdd(&cnt[q][k], 1);
            slab[pos] = make_int2((cols[e] << LBITS) | (r & (BROWS - 1)),
                                  __float_as_int(vals[e] * FXS32));   // exact prescale
        }
    }
}

__global__ void k_bscan2(const int* __restrict__ bcur, int* __restrict__ bbase,
                         int* __restrict__ row_ptr) {
    __shared__ int lds[256];
    int tid = threadIdx.x;
    int c = (tid < NBUCKET) ? (bcur[tid] - tid * BCAP) : 0;
    lds[tid] = c;
    __syncthreads();
    for (int off = 1; off < 256; off <<= 1) {
        int add = (tid >= off) ? lds[tid - off] : 0;
        __syncthreads();
        lds[tid] += add;
        __syncthreads();
    }
    if (tid < NBUCKET) bbase[tid] = lds[tid] - c;   // tight base into packed
    if (tid == 0) { bbase[NBUCKET] = NNZ_CNT; row_ptr[N_NEURONS] = NNZ_CNT; }
}

__global__ void __launch_bounds__(1024) k_passB(const int* __restrict__ bcur,
                                                const int* __restrict__ bbase,
                                                const int2* __restrict__ slab,
                                                int2* __restrict__ packed,
                                                int* __restrict__ row_ptr) {
    __shared__ int cnt[BROWS];
    __shared__ int scn[BROWS];
    const int tid = threadIdx.x;
    const int k  = blockIdx.x;
    const int r0 = k * BROWS;
    const int nr = min(BROWS, N_NEURONS - r0);
    const int S0 = k * BCAP;                       // slab region
    const int SC = bcur[k] - S0;                   // exact bucket count
    const int Q0 = bbase[k];                       // tight packed base
    for (int i = tid; i < BROWS; i += 1024) cnt[i] = 0;
    __syncthreads();
    for (int i = tid; i < SC; i += 1024)
        atomicAdd(&cnt[slab[S0 + i].x & (BROWS - 1)], 1);
    __syncthreads();
    if (tid < BROWS) scn[tid] = cnt[tid];
    __syncthreads();
    for (int off = 1; off < BROWS; off <<= 1) {
        int add = (tid < BROWS && tid >= off) ? scn[tid - off] : 0;
        __syncthreads();
        if (tid < BROWS) scn[tid] += add;
        __syncthreads();
    }
    if (tid < BROWS) {
        int ex = Q0 + scn[tid] - cnt[tid];          // exclusive row base (tight)
        if (tid < nr) row_ptr[r0 + tid] = ex;
        scn[tid] = ex;                              // cursor
    }
    __syncthreads();
    for (int i = tid; i < SC; i += 1024) {
        int2 pe = slab[S0 + i];
        int d = atomicAdd(&scn[pe.x & (BROWS - 1)], 1);
        packed[d] = make_int2(pe.x >> LBITS, pe.y); // (col, prescaled val)
    }
}

// ---------------- fused per-layer SpMM + activation ----------------
__global__ void __launch_bounds__(256) k_layer(const int* __restrict__ row_ptr,
                                               const int2* __restrict__ packed,
                                               const float* __restrict__ state_in,
                                               const float* __restrict__ inp,
                                               float* __restrict__ plane_out,
                                               int t) {
    __shared__ int2 ebuf[16][17];               // [group][slot], +1 pad
    const int tid = threadIdx.x;
    const int g = tid >> 4, b = tid & 15;
    const int r = blockIdx.x * 16 + g;          // 6250*16 == N_NEURONS exactly
    const int s = row_ptr[r], e = row_ptr[r + 1];
    int acc = 0;
    int idx0 = s + b;
    int2 pe = (idx0 < e) ? packed[idx0] : make_int2(0, 0);
    for (int base = s; base < e; base += 16) {
        int nidx = base + 16 + b;               // prefetch next batch NOW
        int2 pe_next = (nidx < e) ? packed[nidx] : make_int2(0, 0);
        ebuf[g][b] = pe;                        // wave-lockstep, in-order DS pipe
        #pragma unroll
        for (int j = 0; j < 16; ++j) {
            int2 q = ebuf[g][j];                // 16-lane same-address broadcast read
            float prod = __int_as_float(q.y) * state_in[q.x * BATCH + b];
            acc += __float2int_rn(prod);        // UNBIASED quantization at 2^-28
        }
        pe = pe_next;
    }
    float y = (float)acc * FXI32;
    float a = activate(y);
    if (t < T_LAYERS - 1) {
        if (r < N_SENSORY) a += thresh_clamp_inp(inp[b * ST + r * T_LAYERS + (t + 1)]);
        a = fminf(a, 1.0f);                     // off-sensory no-op (|tanh|<1)
    }
    plane_out[r * BATCH + b] = a;
}

// ---------------- planes[t][n][b] -> out[b][n][t] ----------------
__global__ void k_out(const float* __restrict__ planes, float* __restrict__ out) {
    int i = blockIdx.x * blockDim.x + threadIdx.x;
    if (i >= NB) return;
    int n = i >> 4, b = i & 15;
    float4 o0, o1;
    o0.x = planes[0 * NB + i]; o0.y = planes[1 * NB + i];
    o0.z = planes[2 * NB + i]; o0.w = planes[3 * NB + i];
    o1.x = planes[4 * NB + i]; o1.y = planes[5 * NB + i];
    o1.z = planes[6 * NB + i]; o1.w = planes[7 * NB + i];
    float4* dst = (float4*)&out[b * NT + n * T_LAYERS];
    dst[0] = o0; dst[1] = o1;
}

// ---------------- fallback (atomic fixed-point path, 19.2 MB ws) ----------------
__global__ void k2_init(const float* __restrict__ inp, float* __restrict__ state,
                        long long* __restrict__ acc) {
    int stride = gridDim.x * blockDim.x;
    for (int i = blockIdx.x * blockDim.x + threadIdx.x; i < NB; i += stride) {
        int n = i >> 4, b = i & 15;
        float v = 0.0f;
        if (n < N_SENSORY) v = thresh_clamp_inp(inp[b * ST + n * T_LAYERS + 0]);
        state[i] = v;
        acc[i]   = 0LL;
    }
}
__global__ void __launch_bounds__(256) k2_spmm(const float* __restrict__ vals,
                                               const int* __restrict__ rows,
                                               const int* __restrict__ cols,
                                               const float* __restrict__ state,
                                               long long* acc) {
    int tid = blockIdx.x * blockDim.x + threadIdx.x;
    int b = tid & 15;
    int e = tid >> 4;
    int estride = (gridDim.x * blockDim.x) >> 4;
    for (; e < NNZ_CNT; e += estride) {
        float xv = state[cols[e] * BATCH + b];
        long long fx = llrintf(vals[e] * xv * FXSCALE);
        if (fx != 0LL)
            atomicAdd((unsigned long long*)&acc[rows[e] * BATCH + b], (unsigned long long)fx);
    }
}
__global__ void k2_act_inject(long long* acc, const float* __restrict__ inp,
                              float* __restrict__ state, float* __restrict__ out, int t) {
    int stride = gridDim.x * blockDim.x;
    for (int i = blockIdx.x * blockDim.x + threadIdx.x; i < NB; i += stride) {
        int n = i >> 4, b = i & 15;
        float y = (float)((double)acc[i] * FXINV);
        acc[i] = 0LL;
        float v = activate(y);
        if (n < N_SENSORY) v += thresh_clamp_inp(inp[b * ST + n * T_LAYERS + (t + 1)]);
        v = fminf(v, 1.0f);
        state[i] = v;
        out[b * NT + n * T_LAYERS + t] = v;
    }
}
__global__ void k2_act_final(const long long* __restrict__ acc, float* __restrict__ out) {
    int stride = gridDim.x * blockDim.x;
    for (int i = blockIdx.x * blockDim.x + threadIdx.x; i < NB; i += stride) {
        int n = i >> 4, b = i & 15;
        float y = (float)((double)acc[i] * FXINV);
        out[b * NT + n * T_LAYERS + (T_LAYERS - 1)] = activate(y);
    }
}

extern "C" void kernel_launch(void* const* d_in, const int* in_sizes, int n_in,
                              void* d_out, int out_size, void* d_ws, size_t ws_size,
                              hipStream_t stream) {
    const float* inputs = (const float*)d_in[0];
    const float* vals   = (const float*)d_in[1];
    const int*   rows   = (const int*)  d_in[2];
    const int*   cols   = (const int*)  d_in[3];
    float* out = (float*)d_out;

    const size_t sz_planes = (size_t)T_LAYERS * NB * 4;   // 51.2 MB (slab 28.9MB aliases planes[0..4])
    const size_t sz_packed = (size_t)NNZ_CNT * 8;         // 25.6 MB
    const size_t sz_rowptr = ((size_t)N_NEURONS + 2) * 4;
    const size_t sz_bt     = (size_t)(NBUCKET + 8) * 4;
    const size_t REQ = sz_planes + sz_packed + sz_rowptr + 2 * sz_bt;

    const int block = 256;

    if (ws_size >= REQ) {
        char* ws = (char*)d_ws;
        float* planes  = (float*)ws;
        int2*  packed  = (int2*)(ws + sz_planes);
        int*   row_ptr = (int*)(ws + sz_planes + sz_packed);
        int*   bbase   = (int*)(ws + sz_planes + sz_packed + sz_rowptr);
        int*   bcur    = (int*)(ws + sz_planes + sz_packed + sz_rowptr + sz_bt);
        float* state0  = planes + (size_t)(T_LAYERS - 1) * NB;  // planes[7], consumed at t=0
        int2*  slab    = (int2*)planes;   // 28.9 MB build scratch; dead before layers

        const int grid_nb = (NB + block - 1) / block;           // 6250

        k_init<<<grid_nb, block, 0, stream>>>(inputs, state0, bcur);
        k_passA<<<NBLK_A, 1024, 0, stream>>>(vals, rows, cols, bcur, slab);
        k_bscan2<<<1, 256, 0, stream>>>(bcur, bbase, row_ptr);
        k_passB<<<NBUCKET, 1024, 0, stream>>>(bcur, bbase, slab, packed, row_ptr);

        for (int t = 0; t < T_LAYERS; ++t) {
            const float* sin_ = (t == 0) ? state0 : planes + (size_t)(t - 1) * NB;
            k_layer<<<grid_nb, block, 0, stream>>>(row_ptr, packed, sin_, inputs,
                                                   planes + (size_t)t * NB, t);
        }
        k_out<<<grid_nb, block, 0, stream>>>(planes, out);
    } else {
        long long* acc   = (long long*)d_ws;
        float*     state = (float*)(acc + NB);
        const int grid_ew = 2048, grid_sp = 2048;
        k2_init<<<grid_ew, block, 0, stream>>>(inputs, state, acc);
        for (int t = 0; t < T_LAYERS; ++t) {
            k2_spmm<<<grid_sp, block, 0, stream>>>(vals, rows, cols, state, acc);
            if (t < T_LAYERS - 1)
                k2_act_inject<<<grid_ew, block, 0, stream>>>(acc, inputs, state, out, t);
            else
                k2_act_final<<<grid_ew, block, 0, stream>>>(acc, out);
        }
    }
}